// Round 4
// baseline (271.671 us; speedup 1.0000x reference)
//
#include <hip/hip_runtime.h>
#include <cmath>

#define NQ 16
#define NT 8

typedef float f32x4 __attribute__((ext_vector_type(4)));

// order-preserving float->u32 (total order ascending)
__device__ __forceinline__ unsigned ordf(float x) {
    unsigned u = __float_as_uint(x);
    return u ^ ((unsigned)((int)u >> 31) | 0x80000000u);
}
// inverse (keys here are always real query keys, never the empty sentinel)
__device__ __forceinline__ float unordf(unsigned k) {
    unsigned m = (~(unsigned)((int)k >> 31)) | 0x80000000u;
    return __uint_as_float(k ^ m);
}
__device__ __forceinline__ unsigned umin2(unsigned a, unsigned b) { return a < b ? a : b; }

// Intra-quad lane exchange via DPP quad_perm — single VALU op, no LDS pipe.
// xor1: [1,0,3,2] = 0xB1;  xor2: [2,3,0,1] = 0x4E.
__device__ __forceinline__ unsigned dpp_xor1_u(unsigned x) {
    return (unsigned)__builtin_amdgcn_mov_dpp((int)x, 0xB1, 0xF, 0xF, true);
}
__device__ __forceinline__ unsigned dpp_xor2_u(unsigned x) {
    return (unsigned)__builtin_amdgcn_mov_dpp((int)x, 0x4E, 0xF, 0xF, true);
}
__device__ __forceinline__ float dpp_xor1_f(float x) {
    return __uint_as_float(dpp_xor1_u(__float_as_uint(x)));
}

// Exact reference-parity path (rare): recompute the whole row with the
// correctly-rounded double-exp sigmoid and exact float dedup (validated
// bit-exact vs reference, absmax 0.0). Unchanged.
__device__ __noinline__ unsigned exact_mask(
    const float* __restrict__ pred_logits,
    const float* __restrict__ pred_disp,
    const float* __restrict__ targets,
    size_t b)
{
    float tg[NT];
#pragma unroll
    for (int t = 0; t < NT; ++t) {
        float v = targets[b * NT + t];
        tg[t] = (v == 0.0f) ? 1000000.0f : v;
    }
    float C[NQ];
    int   ind[NQ];
#pragma unroll
    for (int n = 0; n < NQ; ++n) {
        float d = pred_disp[b * NQ + n];
        float best = fabsf(d - tg[0]);
        int bi = 0;
#pragma unroll
        for (int t = 1; t < NT; ++t) {
            float e = fabsf(d - tg[t]);
            if (e < best) { best = e; bi = t; }   // strict <: first target wins
        }
        float sig = (float)(1.0 / (1.0 + exp(-(double)pred_logits[b * NQ + n])));
        C[n] = (-sig) + best;                     // same op order as reference
        ind[n] = bi;
    }
    unsigned mask = 0u;
#pragma unroll
    for (int t = 0; t < NT; ++t) {
        int w = 31;
        float bc = 3.0e38f;
#pragma unroll
        for (int n = 0; n < NQ; ++n) {
            bool upd = (ind[n] == t) && (C[n] < bc);  // strict <: first query wins
            bc = upd ? C[n] : bc;
            w  = upd ? n : w;
        }
        mask |= (1u << w);
    }
    return mask;
}

struct QuadOut { f32x4 oi, ol; };

// One quad-lane's worth of work for one row (validated round-3 body).
// Query-centric dedup: per-target BEST keys only (8 named scalars, never
// arrays -> nothing can be demoted to LDS/scratch), butterfly-min over the
// quad via DPP; label = (my key == best of my target). Guard: non-winner
// within thr of its target's best fires need_slow (equivalent to the
// validated best/2nd-best gap guard); OR-reduced so the branch is
// quad-uniform.
__device__ __forceinline__ QuadOut quad_compute(
    int j, size_t b, f32x4 d4, f32x4 l4, f32x4 t4,
    const float* __restrict__ pred_logits,
    const float* __restrict__ pred_disp,
    const float* __restrict__ targets)
{
    const float BIGF = 1000000.0f;

    // sentinel-replace my half of targets, swap halves across lane^1 (DPP)
    float tv0 = (t4.x == 0.0f) ? BIGF : t4.x;
    float tv1 = (t4.y == 0.0f) ? BIGF : t4.y;
    float tv2 = (t4.z == 0.0f) ? BIGF : t4.z;
    float tv3 = (t4.w == 0.0f) ? BIGF : t4.w;
    float ov0 = dpp_xor1_f(tv0);
    float ov1 = dpp_xor1_f(tv1);
    float ov2 = dpp_xor1_f(tv2);
    float ov3 = dpp_xor1_f(tv3);

    const bool lo = ((j & 1) == 0);
    float tg[NT];
    tg[0] = lo ? tv0 : ov0;  tg[1] = lo ? tv1 : ov1;
    tg[2] = lo ? tv2 : ov2;  tg[3] = lo ? tv3 : ov3;
    tg[4] = lo ? ov0 : tv0;  tg[5] = lo ? ov1 : tv1;
    tg[6] = lo ? ov2 : tv2;  tg[7] = lo ? ov3 : tv3;

    // my 4 queries: exact argmin over 8 targets + fast-sigmoid key
    int      ind[4];
    unsigned qk[4];
    {
        float dv[4] = {d4.x, d4.y, d4.z, d4.w};
        float lv[4] = {l4.x, l4.y, l4.z, l4.w};
#pragma unroll
        for (int i = 0; i < 4; ++i) {
            float d = dv[i];
            float best = fabsf(d - tg[0]);
            int bi = 0;
#pragma unroll
            for (int t = 1; t < NT; ++t) {
                float e = fabsf(d - tg[t]);
                if (e < best) { best = e; bi = t; }   // exact: matches reference
            }
            ind[i] = bi;
            float sig = __builtin_amdgcn_rcpf(1.0f + __expf(-lv[i]));
            float C = best - sig;
            int n = 4 * j + i;                        // global query id
            qk[i] = (ordf(C) & ~31u) | (unsigned)n;   // key: C order + query id
        }
    }

    // per-target best over my 4 queries (min-only, named scalars)
    auto localbest = [&](int t) -> unsigned {
        unsigned bc = 0xFFFFFFFFu;
#pragma unroll
        for (int i = 0; i < 4; ++i) {
            unsigned x = (ind[i] == t) ? qk[i] : 0xFFFFFFFFu;
            bc = umin2(bc, x);
        }
        return bc;
    };
    unsigned bc0 = localbest(0), bc1 = localbest(1);
    unsigned bc2 = localbest(2), bc3 = localbest(3);
    unsigned bc4 = localbest(4), bc5 = localbest(5);
    unsigned bc6 = localbest(6), bc7 = localbest(7);

    // butterfly min over the quad: 2 DPP + 2 min per target
    auto quadmin = [](unsigned v) -> unsigned {
        v = umin2(v, dpp_xor1_u(v));
        v = umin2(v, dpp_xor2_u(v));
        return v;
    };
    bc0 = quadmin(bc0); bc1 = quadmin(bc1);
    bc2 = quadmin(bc2); bc3 = quadmin(bc3);
    bc4 = quadmin(bc4); bc5 = quadmin(bc5);
    bc6 = quadmin(bc6); bc7 = quadmin(bc7);

    // select bc[ind[i]] via 3-level cndmask tree (scalars only)
    auto selbc = [&](int id) -> unsigned {
        unsigned a0 = (id & 1) ? bc1 : bc0;
        unsigned a1 = (id & 1) ? bc3 : bc2;
        unsigned a2 = (id & 1) ? bc5 : bc4;
        unsigned a3 = (id & 1) ? bc7 : bc6;
        unsigned c0 = (id & 2) ? a1 : a0;
        unsigned c1 = (id & 2) ? a3 : a2;
        return (id & 4) ? c1 : c0;
    };

    bool  ns = false;
    float lab0, lab1, lab2, lab3;
    {
        float labs[4];
#pragma unroll
        for (int i = 0; i < 4; ++i) {
            unsigned bsel = selbc(ind[i]);
            bool isw = (qk[i] == bsel);
            // guard in float domain: non-winner within thr of its target's
            // best -> ambiguous under fast sigmoid + 5-bit key clearing.
            float Cf  = unordf(qk[i]);
            float bf  = unordf(bsel);
            float thr = fmaf(fabsf(bf), 1.6e-5f, 2.0e-4f);
            ns = ns || (!isw && ((Cf - bf) < thr));
            labs[i] = isw ? 1.0f : 0.0f;
        }
        lab0 = labs[0]; lab1 = labs[1]; lab2 = labs[2]; lab3 = labs[3];
    }

    // OR-reduce need_slow over the quad -> uniform branch, no divergence
    unsigned nsw = ns ? 1u : 0u;
    nsw |= dpp_xor1_u(nsw);
    nsw |= dpp_xor2_u(nsw);
    if (__builtin_expect(nsw != 0u, 0)) {
        unsigned mask = exact_mask(pred_logits, pred_disp, targets, b);
        lab0 = (float)((mask >> (4 * j + 0)) & 1u);
        lab1 = (float)((mask >> (4 * j + 1)) & 1u);
        lab2 = (float)((mask >> (4 * j + 2)) & 1u);
        lab3 = (float)((mask >> (4 * j + 3)) & 1u);
    }

    QuadOut o;
    o.oi.x = (float)ind[0]; o.oi.y = (float)ind[1];
    o.oi.z = (float)ind[2]; o.oi.w = (float)ind[3];
    o.ol.x = lab0; o.ol.y = lab1; o.ol.z = lab2; o.ol.w = lab3;
    return o;
}

// TWO rows per thread for 2x memory-level parallelism: thread t handles
// quad-lane t and quad-lane t+half (half = 2B rounded to a multiple of 4,
// so the second quad stays aligned to a DPP lane-quad). All six loads are
// issued up front — 6 independent loads in flight per thread instead of 3.
// Every access stays 16 B/lane perfectly contiguous (the half-offset is
// wave-uniform, unlike round-1's broken stride-2 layout).
// Outputs use nontemporal full-line stores: no L2/L3 allocation, so the
// ~160 MB input set stays L3-resident instead of being evicted by 134 MB
// of write-allocate (round-3 steady state: FETCH = 82 MB = evicted inputs).
__global__ __launch_bounds__(256) void nearest_matcher_kernel(
    const float* __restrict__ pred_logits,
    const float* __restrict__ pred_disp,
    const float* __restrict__ targets,
    float* __restrict__ out_idx,
    float* __restrict__ out_lab,
    unsigned long long half,
    unsigned long long total)
{
    const size_t t = (size_t)blockIdx.x * blockDim.x + threadIdx.x;
    if (t >= (size_t)half) return;
    const size_t g1 = t;
    const size_t g2 = t + (size_t)half;
    const bool  do2 = g2 < (size_t)total;

    // ---- issue all loads up front (coalesced 16 B/lane) ----
    f32x4 d4a = ((const f32x4*)pred_disp)[g1];
    f32x4 l4a = ((const f32x4*)pred_logits)[g1];
    f32x4 t4a = ((const f32x4*)targets)[(g1 >> 2) * 2 + (size_t)(g1 & 1)];
    f32x4 d4b, l4b, t4b;
    if (do2) {
        d4b = ((const f32x4*)pred_disp)[g2];
        l4b = ((const f32x4*)pred_logits)[g2];
        t4b = ((const f32x4*)targets)[(g2 >> 2) * 2 + (size_t)(g2 & 1)];
    }

    // ---- row A ----
    QuadOut a = quad_compute((int)(g1 & 3), g1 >> 2, d4a, l4a, t4a,
                             pred_logits, pred_disp, targets);
    __builtin_nontemporal_store(a.oi, ((f32x4*)out_idx) + g1);
    __builtin_nontemporal_store(a.ol, ((f32x4*)out_lab) + g1);

    // ---- row B ----
    if (do2) {
        QuadOut c = quad_compute((int)(g2 & 3), g2 >> 2, d4b, l4b, t4b,
                                 pred_logits, pred_disp, targets);
        __builtin_nontemporal_store(c.oi, ((f32x4*)out_idx) + g2);
        __builtin_nontemporal_store(c.ol, ((f32x4*)out_lab) + g2);
    }
}

extern "C" void kernel_launch(void* const* d_in, const int* in_sizes, int n_in,
                              void* d_out, int out_size, void* d_ws, size_t ws_size,
                              hipStream_t stream) {
    const float* pred_logits = (const float*)d_in[0];
    const float* pred_disp   = (const float*)d_in[1];
    const float* targets     = (const float*)d_in[2];

    int B = in_sizes[0] / NQ;

    float* out_idx = (float*)d_out;              // indices [B, NQ] flat, first
    float* out_lab = out_idx + (size_t)B * NQ;   // labels  [B, NQ] flat, second

    const unsigned long long total = (unsigned long long)B * 4; // quad-lanes
    unsigned long long half = (total / 2 + 3ull) & ~3ull;       // quad-aligned
    if (half == 0) half = 4;                                    // tiny-B safety

    const int threads = 256;
    const int blocks = (int)((half + threads - 1) / threads);
    hipLaunchKernelGGL(nearest_matcher_kernel, dim3(blocks), dim3(threads), 0, stream,
                       pred_logits, pred_disp, targets, out_idx, out_lab, half, total);
}

// Round 5
// 261.868 us; speedup vs baseline: 1.0374x; 1.0374x over previous
//
#include <hip/hip_runtime.h>
#include <cmath>

#define NQ 16
#define NT 8

typedef float f32x4 __attribute__((ext_vector_type(4)));

// order-preserving float->u32 (total order ascending)
__device__ __forceinline__ unsigned ordf(float x) {
    unsigned u = __float_as_uint(x);
    return u ^ ((unsigned)((int)u >> 31) | 0x80000000u);
}
// inverse (keys here are always real query keys, never the empty sentinel)
__device__ __forceinline__ float unordf(unsigned k) {
    unsigned m = (~(unsigned)((int)k >> 31)) | 0x80000000u;
    return __uint_as_float(k ^ m);
}
__device__ __forceinline__ unsigned umin2(unsigned a, unsigned b) { return a < b ? a : b; }

// Intra-quad lane exchange via DPP quad_perm — single VALU op, no LDS pipe.
// xor1: [1,0,3,2] = 0xB1;  xor2: [2,3,0,1] = 0x4E.
__device__ __forceinline__ unsigned dpp_xor1_u(unsigned x) {
    return (unsigned)__builtin_amdgcn_mov_dpp((int)x, 0xB1, 0xF, 0xF, true);
}
__device__ __forceinline__ unsigned dpp_xor2_u(unsigned x) {
    return (unsigned)__builtin_amdgcn_mov_dpp((int)x, 0x4E, 0xF, 0xF, true);
}
__device__ __forceinline__ float dpp_xor1_f(float x) {
    return __uint_as_float(dpp_xor1_u(__float_as_uint(x)));
}

// Exact reference-parity path (rare): recompute the whole row with the
// correctly-rounded double-exp sigmoid and exact float dedup (validated
// bit-exact vs reference, absmax 0.0). Unchanged.
__device__ __noinline__ unsigned exact_mask(
    const float* __restrict__ pred_logits,
    const float* __restrict__ pred_disp,
    const float* __restrict__ targets,
    size_t b)
{
    float tg[NT];
#pragma unroll
    for (int t = 0; t < NT; ++t) {
        float v = targets[b * NT + t];
        tg[t] = (v == 0.0f) ? 1000000.0f : v;
    }
    float C[NQ];
    int   ind[NQ];
#pragma unroll
    for (int n = 0; n < NQ; ++n) {
        float d = pred_disp[b * NQ + n];
        float best = fabsf(d - tg[0]);
        int bi = 0;
#pragma unroll
        for (int t = 1; t < NT; ++t) {
            float e = fabsf(d - tg[t]);
            if (e < best) { best = e; bi = t; }   // strict <: first target wins
        }
        float sig = (float)(1.0 / (1.0 + exp(-(double)pred_logits[b * NQ + n])));
        C[n] = (-sig) + best;                     // same op order as reference
        ind[n] = bi;
    }
    unsigned mask = 0u;
#pragma unroll
    for (int t = 0; t < NT; ++t) {
        int w = 31;
        float bc = 3.0e38f;
#pragma unroll
        for (int n = 0; n < NQ; ++n) {
            bool upd = (ind[n] == t) && (C[n] < bc);  // strict <: first query wins
            bc = upd ? C[n] : bc;
            w  = upd ? n : w;
        }
        mask |= (1u << w);
    }
    return mask;
}

struct QuadOut { f32x4 oi, ol; };

// One quad-lane's worth of work for one row (validated round-3 body).
// Query-centric dedup: per-target BEST keys only (8 named scalars, never
// arrays -> nothing can be demoted to LDS/scratch), butterfly-min over the
// quad via DPP; label = (my key == best of my target). Guard: non-winner
// within thr of its target's best fires need_slow (equivalent to the
// validated best/2nd-best gap guard); OR-reduced so the branch is
// quad-uniform.
__device__ __forceinline__ QuadOut quad_compute(
    int j, size_t b, f32x4 d4, f32x4 l4, f32x4 t4,
    const float* __restrict__ pred_logits,
    const float* __restrict__ pred_disp,
    const float* __restrict__ targets)
{
    const float BIGF = 1000000.0f;

    // sentinel-replace my half of targets, swap halves across lane^1 (DPP)
    float tv0 = (t4.x == 0.0f) ? BIGF : t4.x;
    float tv1 = (t4.y == 0.0f) ? BIGF : t4.y;
    float tv2 = (t4.z == 0.0f) ? BIGF : t4.z;
    float tv3 = (t4.w == 0.0f) ? BIGF : t4.w;
    float ov0 = dpp_xor1_f(tv0);
    float ov1 = dpp_xor1_f(tv1);
    float ov2 = dpp_xor1_f(tv2);
    float ov3 = dpp_xor1_f(tv3);

    const bool lo = ((j & 1) == 0);
    float tg[NT];
    tg[0] = lo ? tv0 : ov0;  tg[1] = lo ? tv1 : ov1;
    tg[2] = lo ? tv2 : ov2;  tg[3] = lo ? tv3 : ov3;
    tg[4] = lo ? ov0 : tv0;  tg[5] = lo ? ov1 : tv1;
    tg[6] = lo ? ov2 : tv2;  tg[7] = lo ? ov3 : tv3;

    // my 4 queries: exact argmin over 8 targets + fast-sigmoid key
    int      ind[4];
    unsigned qk[4];
    {
        float dv[4] = {d4.x, d4.y, d4.z, d4.w};
        float lv[4] = {l4.x, l4.y, l4.z, l4.w};
#pragma unroll
        for (int i = 0; i < 4; ++i) {
            float d = dv[i];
            float best = fabsf(d - tg[0]);
            int bi = 0;
#pragma unroll
            for (int t = 1; t < NT; ++t) {
                float e = fabsf(d - tg[t]);
                if (e < best) { best = e; bi = t; }   // exact: matches reference
            }
            ind[i] = bi;
            float sig = __builtin_amdgcn_rcpf(1.0f + __expf(-lv[i]));
            float C = best - sig;
            int n = 4 * j + i;                        // global query id
            qk[i] = (ordf(C) & ~31u) | (unsigned)n;   // key: C order + query id
        }
    }

    // per-target best over my 4 queries (min-only, named scalars)
    auto localbest = [&](int t) -> unsigned {
        unsigned bc = 0xFFFFFFFFu;
#pragma unroll
        for (int i = 0; i < 4; ++i) {
            unsigned x = (ind[i] == t) ? qk[i] : 0xFFFFFFFFu;
            bc = umin2(bc, x);
        }
        return bc;
    };
    unsigned bc0 = localbest(0), bc1 = localbest(1);
    unsigned bc2 = localbest(2), bc3 = localbest(3);
    unsigned bc4 = localbest(4), bc5 = localbest(5);
    unsigned bc6 = localbest(6), bc7 = localbest(7);

    // butterfly min over the quad: 2 DPP + 2 min per target
    auto quadmin = [](unsigned v) -> unsigned {
        v = umin2(v, dpp_xor1_u(v));
        v = umin2(v, dpp_xor2_u(v));
        return v;
    };
    bc0 = quadmin(bc0); bc1 = quadmin(bc1);
    bc2 = quadmin(bc2); bc3 = quadmin(bc3);
    bc4 = quadmin(bc4); bc5 = quadmin(bc5);
    bc6 = quadmin(bc6); bc7 = quadmin(bc7);

    // select bc[ind[i]] via 3-level cndmask tree (scalars only)
    auto selbc = [&](int id) -> unsigned {
        unsigned a0 = (id & 1) ? bc1 : bc0;
        unsigned a1 = (id & 1) ? bc3 : bc2;
        unsigned a2 = (id & 1) ? bc5 : bc4;
        unsigned a3 = (id & 1) ? bc7 : bc6;
        unsigned c0 = (id & 2) ? a1 : a0;
        unsigned c1 = (id & 2) ? a3 : a2;
        return (id & 4) ? c1 : c0;
    };

    bool  ns = false;
    float lab0, lab1, lab2, lab3;
    {
        float labs[4];
#pragma unroll
        for (int i = 0; i < 4; ++i) {
            unsigned bsel = selbc(ind[i]);
            bool isw = (qk[i] == bsel);
            // guard in float domain: non-winner within thr of its target's
            // best -> ambiguous under fast sigmoid + 5-bit key clearing.
            float Cf  = unordf(qk[i]);
            float bf  = unordf(bsel);
            float thr = fmaf(fabsf(bf), 1.6e-5f, 2.0e-4f);
            ns = ns || (!isw && ((Cf - bf) < thr));
            labs[i] = isw ? 1.0f : 0.0f;
        }
        lab0 = labs[0]; lab1 = labs[1]; lab2 = labs[2]; lab3 = labs[3];
    }

    // OR-reduce need_slow over the quad -> uniform branch, no divergence
    unsigned nsw = ns ? 1u : 0u;
    nsw |= dpp_xor1_u(nsw);
    nsw |= dpp_xor2_u(nsw);
    if (__builtin_expect(nsw != 0u, 0)) {
        unsigned mask = exact_mask(pred_logits, pred_disp, targets, b);
        lab0 = (float)((mask >> (4 * j + 0)) & 1u);
        lab1 = (float)((mask >> (4 * j + 1)) & 1u);
        lab2 = (float)((mask >> (4 * j + 2)) & 1u);
        lab3 = (float)((mask >> (4 * j + 3)) & 1u);
    }

    QuadOut o;
    o.oi.x = (float)ind[0]; o.oi.y = (float)ind[1];
    o.oi.z = (float)ind[2]; o.oi.w = (float)ind[3];
    o.ol.x = lab0; o.ol.y = lab1; o.ol.z = lab2; o.ol.w = lab3;
    return o;
}

// TWO rows per thread for 2x memory-level parallelism. Round-4 failure mode:
// VGPR stayed 44 -> compiler SANK the row-B loads below row-A compute (its
// register-pressure heuristic), so no loads ever overlapped and wave count
// was halved for nothing. Fix: __builtin_amdgcn_sched_barrier(0) after all
// six loads — nothing may cross it, so all 6 VMEM ops issue first. Expected
// codegen: s_waitcnt vmcnt(3) before row-A compute (row-B's loads stay in
// flight under ~1500 cy of row-A VALU), vmcnt(0) only before row-B.
// Outstanding misses/wave: 3 -> 6. The latency*MLP model (13 waves/CU x 3
// misses x 64 B / ~600 cy = 2.6 TB/s) matches the measured 2.5 TB/s, so
// doubling MLP should raise achieved BW toward ~4 TB/s.
// Stores are plain (NT proven byte-identical neutral in round 4).
__global__ __launch_bounds__(256) void nearest_matcher_kernel(
    const float* __restrict__ pred_logits,
    const float* __restrict__ pred_disp,
    const float* __restrict__ targets,
    float* __restrict__ out_idx,
    float* __restrict__ out_lab,
    unsigned long long half,
    unsigned long long total)
{
    const size_t t = (size_t)blockIdx.x * blockDim.x + threadIdx.x;
    if (t >= (size_t)half) return;
    const size_t g1 = t;
    const size_t g2 = t + (size_t)half;
    const bool  do2 = g2 < (size_t)total;   // all-true except possible tail wave

    // ---- issue ALL loads up front (coalesced 16 B/lane) ----
    f32x4 d4a = ((const f32x4*)pred_disp)[g1];
    f32x4 l4a = ((const f32x4*)pred_logits)[g1];
    f32x4 t4a = ((const f32x4*)targets)[(g1 >> 2) * 2 + (size_t)(g1 & 1)];
    f32x4 d4b = {0,0,0,0}, l4b = {0,0,0,0}, t4b = {0,0,0,0};
    if (__builtin_expect(do2, 1)) {
        d4b = ((const f32x4*)pred_disp)[g2];
        l4b = ((const f32x4*)pred_logits)[g2];
        t4b = ((const f32x4*)targets)[(g2 >> 2) * 2 + (size_t)(g2 & 1)];
    }
    // Hard scheduling fence: the six loads above may not sink below this
    // point; row-B data stays in flight during row-A compute.
    __builtin_amdgcn_sched_barrier(0);

    // ---- row A ----
    QuadOut a = quad_compute((int)(g1 & 3), g1 >> 2, d4a, l4a, t4a,
                             pred_logits, pred_disp, targets);
    ((f32x4*)out_idx)[g1] = a.oi;
    ((f32x4*)out_lab)[g1] = a.ol;

    // ---- row B ----
    if (__builtin_expect(do2, 1)) {
        QuadOut c = quad_compute((int)(g2 & 3), g2 >> 2, d4b, l4b, t4b,
                                 pred_logits, pred_disp, targets);
        ((f32x4*)out_idx)[g2] = c.oi;
        ((f32x4*)out_lab)[g2] = c.ol;
    }
}

extern "C" void kernel_launch(void* const* d_in, const int* in_sizes, int n_in,
                              void* d_out, int out_size, void* d_ws, size_t ws_size,
                              hipStream_t stream) {
    const float* pred_logits = (const float*)d_in[0];
    const float* pred_disp   = (const float*)d_in[1];
    const float* targets     = (const float*)d_in[2];

    int B = in_sizes[0] / NQ;

    float* out_idx = (float*)d_out;              // indices [B, NQ] flat, first
    float* out_lab = out_idx + (size_t)B * NQ;   // labels  [B, NQ] flat, second

    const unsigned long long total = (unsigned long long)B * 4; // quad-lanes
    unsigned long long half = (total / 2 + 3ull) & ~3ull;       // quad-aligned
    if (half == 0) half = 4;                                    // tiny-B safety

    const int threads = 256;
    const int blocks = (int)((half + threads - 1) / threads);
    hipLaunchKernelGGL(nearest_matcher_kernel, dim3(blocks), dim3(threads), 0, stream,
                       pred_logits, pred_disp, targets, out_idx, out_lab, half, total);
}